// Round 5
// baseline (291.150 us; speedup 1.0000x reference)
//
#include <hip/hip_runtime.h>

typedef __attribute__((ext_vector_type(8))) short short8;
typedef __attribute__((ext_vector_type(4))) float f32x4;

__device__ __forceinline__ unsigned short f2bf(float x) {  // RNE (prep only)
  union { float f; unsigned u; } v; v.f = x;
  unsigned r = v.u + 0x7fffu + ((v.u >> 16) & 1u);
  return (unsigned short)(r >> 16);
}

// pack 2 f32 -> bf16x2 (a -> low half)
#if __has_builtin(__builtin_amdgcn_cvt_pk_bf16_f32)
__device__ __forceinline__ unsigned pk2(float a, float b) {
  return __builtin_bit_cast(unsigned, __builtin_amdgcn_cvt_pk_bf16_f32(a, b));
}
#else
__device__ __forceinline__ unsigned pk2(float a, float b) {
  union { float f; unsigned u; } x, y; x.f = a; y.f = b;
  return __builtin_amdgcn_perm(y.u + 0x8000u, x.u + 0x8000u, 0x07060302u);
}
#endif

__device__ __forceinline__ short8 u2s8(uint4 u) {
  union { uint4 a; short8 b; } c; c.a = u; return c.b;
}

// compiler-level memory ordering within a wave (DS pipe is in-order per wave;
// these emit no HW instructions, they only pin compile-time ordering)
__device__ __forceinline__ void wave_mem_fence() {
  asm volatile("" ::: "memory");
  __builtin_amdgcn_wave_barrier();
  asm volatile("" ::: "memory");
}

// acos(z)/pi, z clipped to [-1,1].
__device__ __forceinline__ float acos01(float z) {
  float ax = fminf(fabsf(z), 1.0f);
  float t  = __builtin_amdgcn_sqrtf(1.0f - ax);
  float p  = fmaf(ax, fmaf(ax, fmaf(ax, -0.00596110f, 0.02363618f),
                           -0.06751692f), 0.49998766f);
  p *= t;
  return z >= 0.0f ? p : 1.0f - p;
}

// atan2(y,x)/(2pi) + 0.5  in [0,1].
__device__ __forceinline__ float atan2_01(float y, float x) {
  float ax = fabsf(x), ay = fabsf(y);
  float hi = fmaxf(ax, ay), lo = fminf(ax, ay);
  float r  = lo * __builtin_amdgcn_rcpf(fmaxf(hi, 1e-30f));
  float r2 = r * r;
  float p  = fmaf(r2, fmaf(r2, fmaf(r2, fmaf(r2, fmaf(r2,
               -0.0018655370f, 0.0083800422f), -0.018531250f),
                0.030803547f), -0.052940457f), 0.159151323f);
  float q  = r * p;
  q = (ay > ax) ? 0.25f - q : q;
  q = (x < 0.0f) ? 0.5f - q : q;
  return 0.5f + ((y >= 0.0f) ? q : -q);
}

// gaussian one-blob, 4 bins -> two packed dwords
__device__ __forceinline__ uint2 blob4pk(float x) {
  float x4 = x * 4.0f;
  float e0, e1, e2, e3;
  { float t = x4 - 0.5f; e0 = __builtin_amdgcn_exp2f(t * t * -0.72134752f); }
  { float t = x4 - 1.5f; e1 = __builtin_amdgcn_exp2f(t * t * -0.72134752f); }
  { float t = x4 - 2.5f; e2 = __builtin_amdgcn_exp2f(t * t * -0.72134752f); }
  { float t = x4 - 3.5f; e3 = __builtin_amdgcn_exp2f(t * t * -0.72134752f); }
  return make_uint2(pk2(e0, e1), pk2(e2, e3));
}

// bf16 weights in d_ws. Hidden rows permuted by sigma so MFMA C-layout
// feeds the next layer's B-fragment slots directly (verified R2/R3).
__global__ void prep_weights(
    const float* __restrict__ W0, const float* __restrict__ W1,
    const float* __restrict__ W2, const float* __restrict__ W3,
    const float* __restrict__ W4, const float* __restrict__ W5,
    const float* __restrict__ W6, unsigned short* __restrict__ wb)
{
  int idx = blockIdx.x * blockDim.x + threadIdx.x;
  if (idx < 24576) {
    int l = idx >> 12;
    const float* W = (l==0)?W0:(l==1)?W1:(l==2)?W2:(l==3)?W3:(l==4)?W4:W5;
    int p = (idx >> 6) & 63;
    int k = idx & 63;
    int t = p >> 4, q = (p >> 2) & 3, r = p & 3;
    int src = 32*(t>>1) + 8*q + 4*(t&1) + r;
    wb[idx] = f2bf(W[src*64 + k]);
  } else if (idx < 25600) {
    int j = idx - 24576;
    wb[idx] = (j < 192) ? f2bf(W6[j]) : (unsigned short)0;
  }
}

// 32 rows/wave, 4 waves/block (128 rows). X tile is per-wave PRIVATE ->
// no __syncthreads anywhere (DS pipe is in-order per wave). LDS/block =
// 20480 B -> 8 blocks/CU -> 32 waves/CU (8/SIMD), 2x the R3 occupancy.
// Encoding: 2 lanes per row (even=trig half, odd=blob half).
__global__ __launch_bounds__(256) void nrc_mlp(
    const float* __restrict__ P, const float* __restrict__ WI,
    const float* __restrict__ NRM, const float* __restrict__ ALPHA,
    const float* __restrict__ BETA, const float* __restrict__ R,
    const unsigned short* __restrict__ wb, float* __restrict__ out)
{
  __shared__ __align__(16) unsigned short xlds[4][32][72];  // 18432 B
  __shared__ __align__(16) float resf[4][32][4];            //  2048 B
  const int lane = threadIdx.x & 63;
  const int wv   = threadIdx.x >> 6;
  unsigned short (* __restrict__ X)[72] = xlds[wv];
  float (* __restrict__ RES)[4] = resf[wv];
  const int n15 = lane & 15;
  const int q   = lane >> 4;
  const int row0 = (blockIdx.x * 4 + wv) * 32;
  const int aoff = n15*64 + q*8;

  // ---------------- encoding: 2 lanes per row ----------------
  {
    const int row = row0 + (lane >> 1);
    unsigned short* xr = &X[lane >> 1][(lane & 1) * 32];
    if ((lane & 1) == 0) {
      // features 0..31: dims 0,1 sin/cos + dim2 sin + dim2 cos f0,f1
      float s0[6], c0[6], s1[6], c1[6], s2[6], c20, c21;
      float rev = 0.5f * P[row*3+0];
#pragma unroll
      for (int i = 0; i < 6; ++i) {
        float fr = __builtin_amdgcn_fractf(rev);
        s0[i] = __builtin_amdgcn_sinf(fr);
        c0[i] = __builtin_amdgcn_cosf(fr);
        rev = rev + rev;
      }
      rev = 0.5f * P[row*3+1];
#pragma unroll
      for (int i = 0; i < 6; ++i) {
        float fr = __builtin_amdgcn_fractf(rev);
        s1[i] = __builtin_amdgcn_sinf(fr);
        c1[i] = __builtin_amdgcn_cosf(fr);
        rev = rev + rev;
      }
      rev = 0.5f * P[row*3+2];
#pragma unroll
      for (int i = 0; i < 6; ++i) {
        float fr = __builtin_amdgcn_fractf(rev);
        s2[i] = __builtin_amdgcn_sinf(fr);
        if (i == 0) c20 = __builtin_amdgcn_cosf(fr);
        if (i == 1) c21 = __builtin_amdgcn_cosf(fr);
        rev = rev + rev;
      }
      *(uint4*)(xr +  0) = make_uint4(pk2(s0[0],s0[1]), pk2(s0[2],s0[3]),
                                      pk2(s0[4],s0[5]), pk2(c0[0],c0[1]));
      *(uint4*)(xr +  8) = make_uint4(pk2(c0[2],c0[3]), pk2(c0[4],c0[5]),
                                      pk2(s1[0],s1[1]), pk2(s1[2],s1[3]));
      *(uint4*)(xr + 16) = make_uint4(pk2(s1[4],s1[5]), pk2(c1[0],c1[1]),
                                      pk2(c1[2],c1[3]), pk2(c1[4],c1[5]));
      *(uint4*)(xr + 24) = make_uint4(pk2(s2[0],s2[1]), pk2(s2[2],s2[3]),
                                      pk2(s2[4],s2[5]), pk2(c20,c21));
    } else {
      // features 32..63: dim2 cos f2..f5, blobs, alpha/beta/ones
      float c2[4];
      float rev = 2.0f * P[row*3+2];          // 0.5 * pz * 2^2
#pragma unroll
      for (int i = 0; i < 4; ++i) {
        float fr = __builtin_amdgcn_fractf(rev);
        c2[i] = __builtin_amdgcn_cosf(fr);
        rev = rev + rev;
      }
      uint2 bwt, bwp, bnt, bnp, brr;
      {
        float wx = WI[row*3+0], wy = WI[row*3+1], wz = WI[row*3+2];
        bwt = blob4pk(acos01(wz));
        bwp = blob4pk(atan2_01(wy, wx));
      }
      {
        float nx = NRM[row*3+0], ny = NRM[row*3+1], nz = NRM[row*3+2];
        bnt = blob4pk(acos01(nz));
        bnp = blob4pk(atan2_01(ny, nx));
      }
      brr = blob4pk(1.0f - __builtin_amdgcn_exp2f(R[row] * -1.44269504f));
      float a0 = ALPHA[row*3+0], a1 = ALPHA[row*3+1], a2 = ALPHA[row*3+2];
      float e0 = BETA[row*3+0],  e1 = BETA[row*3+1],  e2 = BETA[row*3+2];
      *(uint4*)(xr +  0) = make_uint4(pk2(c2[0],c2[1]), pk2(c2[2],c2[3]),
                                      bwt.x, bwt.y);
      *(uint4*)(xr +  8) = make_uint4(bwp.x, bwp.y, bnt.x, bnt.y);
      *(uint4*)(xr + 16) = make_uint4(bnp.x, bnp.y, brr.x, brr.y);
      *(uint4*)(xr + 24) = make_uint4(pk2(a0,a1), pk2(a2,e0), pk2(e1,e2),
                                      0x3F803F80u);
    }
  }
  wave_mem_fence();   // X writes -> X reads (same wave; DS is in-order)

  // -------- epilogue alpha/beta prefetch (coalesced, hides tail) --------
  float av0, bv0, av1 = 0.f, bv1 = 0.f;
  av0 = ALPHA[row0*3 + lane];
  bv0 = BETA[row0*3 + lane];
  if (lane < 32) {
    av1 = ALPHA[row0*3 + 64 + lane];
    bv1 = BETA[row0*3 + 64 + lane];
  }

  // ---------------- initial B-fragments (2 groups of 16 rows) ----------
  uint4 b0[2], b1[2];
#pragma unroll
  for (int g = 0; g < 2; ++g) {
    b0[g] = *(const uint4*)(&X[g*16 + n15][q*8]);
    b1[g] = *(const uint4*)(&X[g*16 + n15][32 + q*8]);
  }

  // ---------------- 6 hidden layers, register-resident ----------------
#pragma unroll
  for (int l = 0; l < 6; ++l) {
    const unsigned short* W = wb + l*4096;
    short8 a0[4], a1[4];
#pragma unroll
    for (int t = 0; t < 4; ++t) {
      a0[t] = *(const short8*)(W + t*1024 + aoff);
      a1[t] = *(const short8*)(W + t*1024 + 32 + aoff);
    }
#pragma unroll
    for (int g = 0; g < 2; ++g) {
      short8 bb0 = u2s8(b0[g]);
      short8 bb1 = u2s8(b1[g]);
      f32x4 acc[4];
#pragma unroll
      for (int t = 0; t < 4; ++t) {
        f32x4 c = {0.f, 0.f, 0.f, 0.f};
        c = __builtin_amdgcn_mfma_f32_16x16x32_bf16(a0[t], bb0, c, 0, 0, 0);
        c = __builtin_amdgcn_mfma_f32_16x16x32_bf16(a1[t], bb1, c, 0, 0, 0);
        acc[t] = c;
      }
      uint4 n0, n1;
      n0.x = pk2(fmaxf(acc[0][0],0.f), fmaxf(acc[0][1],0.f));
      n0.y = pk2(fmaxf(acc[0][2],0.f), fmaxf(acc[0][3],0.f));
      n0.z = pk2(fmaxf(acc[1][0],0.f), fmaxf(acc[1][1],0.f));
      n0.w = pk2(fmaxf(acc[1][2],0.f), fmaxf(acc[1][3],0.f));
      n1.x = pk2(fmaxf(acc[2][0],0.f), fmaxf(acc[2][1],0.f));
      n1.y = pk2(fmaxf(acc[2][2],0.f), fmaxf(acc[2][3],0.f));
      n1.z = pk2(fmaxf(acc[3][0],0.f), fmaxf(acc[3][1],0.f));
      n1.w = pk2(fmaxf(acc[3][2],0.f), fmaxf(acc[3][3],0.f));
      b0[g] = n0; b1[g] = n1;
    }
  }

  // ---------------- output layer (3x64 padded to 16x64) ----------------
  {
    short8 o0 = *(const short8*)(wb + 24576 + aoff);
    short8 o1 = *(const short8*)(wb + 24576 + 32 + aoff);
#pragma unroll
    for (int g = 0; g < 2; ++g) {
      f32x4 c = {0.f, 0.f, 0.f, 0.f};
      c = __builtin_amdgcn_mfma_f32_16x16x32_bf16(o0, u2s8(b0[g]), c, 0, 0, 0);
      c = __builtin_amdgcn_mfma_f32_16x16x32_bf16(o1, u2s8(b1[g]), c, 0, 0, 0);
      if (q == 0) {
        *(float4*)(&RES[g*16 + n15][0]) = make_float4(c[0], c[1], c[2], 0.f);
      }
    }
  }
  wave_mem_fence();   // RES writes -> RES reads (same wave)

  // ---------------- (alpha+beta) scale + coalesced store ----------------
  {
    int dd = lane;                       // 0..63
    int ri = dd / 3, j = dd - ri*3;
    out[row0*3 + dd] = RES[ri][j] * (av0 + bv0);
  }
  if (lane < 32) {
    int dd = 64 + lane;                  // 64..95
    int ri = dd / 3, j = dd - ri*3;
    out[row0*3 + dd] = RES[ri][j] * (av1 + bv1);
  }
}

extern "C" void kernel_launch(void* const* d_in, const int* in_sizes, int n_in,
                              void* d_out, int out_size, void* d_ws, size_t ws_size,
                              hipStream_t stream) {
  const float* P  = (const float*)d_in[0];
  const float* WI = (const float*)d_in[1];
  const float* NR = (const float*)d_in[2];
  const float* AL = (const float*)d_in[3];
  const float* BE = (const float*)d_in[4];
  const float* R  = (const float*)d_in[5];
  const float* W0 = (const float*)d_in[6];
  const float* W1 = (const float*)d_in[7];
  const float* W2 = (const float*)d_in[8];
  const float* W3 = (const float*)d_in[9];
  const float* W4 = (const float*)d_in[10];
  const float* W5 = (const float*)d_in[11];
  const float* W6 = (const float*)d_in[12];
  unsigned short* wb = (unsigned short*)d_ws;   // 25600 bf16 = 51200 B
  float* out = (float*)d_out;

  prep_weights<<<100, 256, 0, stream>>>(W0, W1, W2, W3, W4, W5, W6, wb);
  nrc_mlp<<<8192, 256, 0, stream>>>(P, WI, NR, AL, BE, R, wb, out);
}

// Round 6
// 209.858 us; speedup vs baseline: 1.3874x; 1.3874x over previous
//
#include <hip/hip_runtime.h>

typedef __attribute__((ext_vector_type(8))) short short8;
typedef __attribute__((ext_vector_type(4))) float f32x4;

__device__ __forceinline__ unsigned short f2bf(float x) {  // RNE (prep only)
  union { float f; unsigned u; } v; v.f = x;
  unsigned r = v.u + 0x7fffu + ((v.u >> 16) & 1u);
  return (unsigned short)(r >> 16);
}

// pack 2 f32 -> bf16x2 (a -> low half)
#if __has_builtin(__builtin_amdgcn_cvt_pk_bf16_f32)
__device__ __forceinline__ unsigned pk2(float a, float b) {
  return __builtin_bit_cast(unsigned, __builtin_amdgcn_cvt_pk_bf16_f32(a, b));
}
#else
__device__ __forceinline__ unsigned pk2(float a, float b) {
  union { float f; unsigned u; } x, y; x.f = a; y.f = b;
  return __builtin_amdgcn_perm(y.u + 0x8000u, x.u + 0x8000u, 0x07060302u);
}
#endif

__device__ __forceinline__ short8 u2s8(uint4 u) {
  union { uint4 a; short8 b; } c; c.a = u; return c.b;
}

// compiler-level ordering within a wave (DS pipe is in-order per wave).
// Emits no HW sync; validated correct in R5.
__device__ __forceinline__ void wave_mem_fence() {
  asm volatile("" ::: "memory");
  __builtin_amdgcn_wave_barrier();
  asm volatile("" ::: "memory");
}

// acos(z)/pi, z clipped to [-1,1].
__device__ __forceinline__ float acos01(float z) {
  float ax = fminf(fabsf(z), 1.0f);
  float t  = __builtin_amdgcn_sqrtf(1.0f - ax);
  float p  = fmaf(ax, fmaf(ax, fmaf(ax, -0.00596110f, 0.02363618f),
                           -0.06751692f), 0.49998766f);
  p *= t;
  return z >= 0.0f ? p : 1.0f - p;
}

// atan2(y,x)/(2pi) + 0.5  in [0,1].
__device__ __forceinline__ float atan2_01(float y, float x) {
  float ax = fabsf(x), ay = fabsf(y);
  float hi = fmaxf(ax, ay), lo = fminf(ax, ay);
  float r  = lo * __builtin_amdgcn_rcpf(fmaxf(hi, 1e-30f));
  float r2 = r * r;
  float p  = fmaf(r2, fmaf(r2, fmaf(r2, fmaf(r2, fmaf(r2,
               -0.0018655370f, 0.0083800422f), -0.018531250f),
                0.030803547f), -0.052940457f), 0.159151323f);
  float q  = r * p;
  q = (ay > ax) ? 0.25f - q : q;
  q = (x < 0.0f) ? 0.5f - q : q;
  return 0.5f + ((y >= 0.0f) ? q : -q);
}

// gaussian one-blob, 4 bins -> two packed dwords
__device__ __forceinline__ uint2 blob4pk(float x) {
  float x4 = x * 4.0f;
  float e0, e1, e2, e3;
  { float t = x4 - 0.5f; e0 = __builtin_amdgcn_exp2f(t * t * -0.72134752f); }
  { float t = x4 - 1.5f; e1 = __builtin_amdgcn_exp2f(t * t * -0.72134752f); }
  { float t = x4 - 2.5f; e2 = __builtin_amdgcn_exp2f(t * t * -0.72134752f); }
  { float t = x4 - 3.5f; e3 = __builtin_amdgcn_exp2f(t * t * -0.72134752f); }
  return make_uint2(pk2(e0, e1), pk2(e2, e3));
}

// bf16 weights in d_ws. Hidden rows permuted by sigma so MFMA C-layout
// feeds the next layer's B-fragment slots directly (verified R2..R5).
__global__ void prep_weights(
    const float* __restrict__ W0, const float* __restrict__ W1,
    const float* __restrict__ W2, const float* __restrict__ W3,
    const float* __restrict__ W4, const float* __restrict__ W5,
    const float* __restrict__ W6, unsigned short* __restrict__ wb)
{
  int idx = blockIdx.x * blockDim.x + threadIdx.x;
  if (idx < 24576) {
    int l = idx >> 12;
    const float* W = (l==0)?W0:(l==1)?W1:(l==2)?W2:(l==3)?W3:(l==4)?W4:W5;
    int p = (idx >> 6) & 63;
    int k = idx & 63;
    int t = p >> 4, q = (p >> 2) & 3, r = p & 3;
    int src = 32*(t>>1) + 8*q + 4*(t&1) + r;
    wb[idx] = f2bf(W[src*64 + k]);
  } else if (idx < 25600) {
    int j = idx - 24576;
    wb[idx] = (j < 192) ? f2bf(W6[j]) : (unsigned short)0;
  }
}

// 64 rows/wave, 4 waves/block (R3 structure = best so far). X is per-wave
// private -> ZERO s_barriers (wave fences only, validated R5). Hoisted zero
// accumulator kills 384 zero-init movs/wave. Epilogue stores float3 direct.
__global__ __launch_bounds__(256, 4) void nrc_mlp(
    const float* __restrict__ P, const float* __restrict__ WI,
    const float* __restrict__ NRM, const float* __restrict__ ALPHA,
    const float* __restrict__ BETA, const float* __restrict__ R,
    const unsigned short* __restrict__ wb, float* __restrict__ out)
{
  __shared__ __align__(16) unsigned short xlds[4][64][72];  // 36864 B
  const int lane = threadIdx.x & 63;
  const int wv   = threadIdx.x >> 6;
  unsigned short (* __restrict__ X)[72] = xlds[wv];
  const int n15 = lane & 15;
  const int q   = lane >> 4;
  const int row0 = (blockIdx.x * 4 + wv) * 64;
  const int aoff = n15*64 + q*8;

  // ---------------- encoding: lane <-> row ----------------
  {
    const int row = row0 + lane;
    unsigned short* xr = &X[lane][0];

    float s0[6], c0[6], s1[6], c1[6], s2[6], c2[6];
    {
      float rev = 0.5f * P[row*3+0];
#pragma unroll
      for (int i = 0; i < 6; ++i) {
        float fr = __builtin_amdgcn_fractf(rev);
        s0[i] = __builtin_amdgcn_sinf(fr);
        c0[i] = __builtin_amdgcn_cosf(fr);
        rev = rev + rev;
      }
      rev = 0.5f * P[row*3+1];
#pragma unroll
      for (int i = 0; i < 6; ++i) {
        float fr = __builtin_amdgcn_fractf(rev);
        s1[i] = __builtin_amdgcn_sinf(fr);
        c1[i] = __builtin_amdgcn_cosf(fr);
        rev = rev + rev;
      }
      rev = 0.5f * P[row*3+2];
#pragma unroll
      for (int i = 0; i < 6; ++i) {
        float fr = __builtin_amdgcn_fractf(rev);
        s2[i] = __builtin_amdgcn_sinf(fr);
        c2[i] = __builtin_amdgcn_cosf(fr);
        rev = rev + rev;
      }
    }
    *(uint4*)(xr +  0) = make_uint4(pk2(s0[0],s0[1]), pk2(s0[2],s0[3]),
                                    pk2(s0[4],s0[5]), pk2(c0[0],c0[1]));
    *(uint4*)(xr +  8) = make_uint4(pk2(c0[2],c0[3]), pk2(c0[4],c0[5]),
                                    pk2(s1[0],s1[1]), pk2(s1[2],s1[3]));
    *(uint4*)(xr + 16) = make_uint4(pk2(s1[4],s1[5]), pk2(c1[0],c1[1]),
                                    pk2(c1[2],c1[3]), pk2(c1[4],c1[5]));
    *(uint4*)(xr + 24) = make_uint4(pk2(s2[0],s2[1]), pk2(s2[2],s2[3]),
                                    pk2(s2[4],s2[5]), pk2(c2[0],c2[1]));

    uint2 bwt, bwp, bnt, bnp, brr;
    {
      float wx = WI[row*3+0], wy = WI[row*3+1], wz = WI[row*3+2];
      bwt = blob4pk(acos01(wz));
      bwp = blob4pk(atan2_01(wy, wx));
    }
    {
      float nx = NRM[row*3+0], ny = NRM[row*3+1], nz = NRM[row*3+2];
      bnt = blob4pk(acos01(nz));
      bnp = blob4pk(atan2_01(ny, nx));
    }
    brr = blob4pk(1.0f - __builtin_amdgcn_exp2f(R[row] * -1.44269504f));

    *(uint4*)(xr + 32) = make_uint4(pk2(c2[2],c2[3]), pk2(c2[4],c2[5]),
                                    bwt.x, bwt.y);
    *(uint4*)(xr + 40) = make_uint4(bwp.x, bwp.y, bnt.x, bnt.y);
    *(uint4*)(xr + 48) = make_uint4(bnp.x, bnp.y, brr.x, brr.y);

    float a0 = ALPHA[row*3+0], a1 = ALPHA[row*3+1], a2 = ALPHA[row*3+2];
    float e0 = BETA[row*3+0],  e1 = BETA[row*3+1],  e2 = BETA[row*3+2];
    *(uint4*)(xr + 56) = make_uint4(pk2(a0,a1), pk2(a2,e0), pk2(e1,e2),
                                    0x3F803F80u);
  }
  wave_mem_fence();   // X writes -> X reads (same wave; DS in-order)

  // ---------------- initial B-fragments (4 groups of 16 rows) ----------
  uint4 b0[4], b1[4];
#pragma unroll
  for (int g = 0; g < 4; ++g) {
    b0[g] = *(const uint4*)(&X[g*16 + n15][q*8]);
    b1[g] = *(const uint4*)(&X[g*16 + n15][32 + q*8]);
  }

  const f32x4 z = {0.f, 0.f, 0.f, 0.f};   // hoisted zero C-operand

  // ---------------- 6 hidden layers, register-resident ----------------
#pragma unroll
  for (int l = 0; l < 6; ++l) {
    const unsigned short* W = wb + l*4096;
    short8 a0[4], a1[4];
#pragma unroll
    for (int t = 0; t < 4; ++t) {
      a0[t] = *(const short8*)(W + t*1024 + aoff);
      a1[t] = *(const short8*)(W + t*1024 + 32 + aoff);
    }
#pragma unroll
    for (int g = 0; g < 4; ++g) {
      short8 bb0 = u2s8(b0[g]);
      short8 bb1 = u2s8(b1[g]);
      f32x4 acc[4];
#pragma unroll
      for (int t = 0; t < 4; ++t) {
        f32x4 c = __builtin_amdgcn_mfma_f32_16x16x32_bf16(a0[t], bb0, z, 0, 0, 0);
        acc[t]  = __builtin_amdgcn_mfma_f32_16x16x32_bf16(a1[t], bb1, c, 0, 0, 0);
      }
      uint4 n0, n1;
      n0.x = pk2(fmaxf(acc[0][0],0.f), fmaxf(acc[0][1],0.f));
      n0.y = pk2(fmaxf(acc[0][2],0.f), fmaxf(acc[0][3],0.f));
      n0.z = pk2(fmaxf(acc[1][0],0.f), fmaxf(acc[1][1],0.f));
      n0.w = pk2(fmaxf(acc[1][2],0.f), fmaxf(acc[1][3],0.f));
      n1.x = pk2(fmaxf(acc[2][0],0.f), fmaxf(acc[2][1],0.f));
      n1.y = pk2(fmaxf(acc[2][2],0.f), fmaxf(acc[2][3],0.f));
      n1.z = pk2(fmaxf(acc[3][0],0.f), fmaxf(acc[3][1],0.f));
      n1.w = pk2(fmaxf(acc[3][2],0.f), fmaxf(acc[3][3],0.f));
      b0[g] = n0; b1[g] = n1;
    }
  }

  // -------- output layer + fused (alpha+beta) scale + direct store --------
  {
    short8 o0 = *(const short8*)(wb + 24576 + aoff);
    short8 o1 = *(const short8*)(wb + 24576 + 32 + aoff);
#pragma unroll
    for (int g = 0; g < 4; ++g) {
      f32x4 c = __builtin_amdgcn_mfma_f32_16x16x32_bf16(o0, u2s8(b0[g]), z, 0, 0, 0);
      c       = __builtin_amdgcn_mfma_f32_16x16x32_bf16(o1, u2s8(b1[g]), c, 0, 0, 0);
      if (q == 0) {
        // lane n15 holds out-neurons 0..2 of row g*16+n15; region is the
        // contiguous 192 B [row0*3 + g*48, +48) across lanes 0..15.
        int base = row0*3 + g*48 + n15*3;
        float3 av = *(const float3*)(ALPHA + base);
        float3 bv = *(const float3*)(BETA + base);
        float3 o;
        o.x = c[0] * (av.x + bv.x);
        o.y = c[1] * (av.y + bv.y);
        o.z = c[2] * (av.z + bv.z);
        *(float3*)(out + base) = o;
      }
    }
  }
}

extern "C" void kernel_launch(void* const* d_in, const int* in_sizes, int n_in,
                              void* d_out, int out_size, void* d_ws, size_t ws_size,
                              hipStream_t stream) {
  const float* P  = (const float*)d_in[0];
  const float* WI = (const float*)d_in[1];
  const float* NR = (const float*)d_in[2];
  const float* AL = (const float*)d_in[3];
  const float* BE = (const float*)d_in[4];
  const float* R  = (const float*)d_in[5];
  const float* W0 = (const float*)d_in[6];
  const float* W1 = (const float*)d_in[7];
  const float* W2 = (const float*)d_in[8];
  const float* W3 = (const float*)d_in[9];
  const float* W4 = (const float*)d_in[10];
  const float* W5 = (const float*)d_in[11];
  const float* W6 = (const float*)d_in[12];
  unsigned short* wb = (unsigned short*)d_ws;   // 25600 bf16 = 51200 B
  float* out = (float*)d_out;

  prep_weights<<<100, 256, 0, stream>>>(W0, W1, W2, W3, W4, W5, W6, wb);
  nrc_mlp<<<4096, 256, 0, stream>>>(P, WI, NR, AL, BE, R, wb, out);
}

// Round 7
// 184.436 us; speedup vs baseline: 1.5786x; 1.1378x over previous
//
#include <hip/hip_runtime.h>

typedef __attribute__((ext_vector_type(8))) short short8;
typedef __attribute__((ext_vector_type(4))) float f32x4;

typedef __attribute__((address_space(3))) unsigned short lds_us;
typedef const __attribute__((address_space(1))) unsigned short glb_us;

__device__ __forceinline__ unsigned short f2bf(float x) {  // RNE (prep only)
  union { float f; unsigned u; } v; v.f = x;
  unsigned r = v.u + 0x7fffu + ((v.u >> 16) & 1u);
  return (unsigned short)(r >> 16);
}

// pack 2 f32 -> bf16x2 (a -> low half)
#if __has_builtin(__builtin_amdgcn_cvt_pk_bf16_f32)
__device__ __forceinline__ unsigned pk2(float a, float b) {
  return __builtin_bit_cast(unsigned, __builtin_amdgcn_cvt_pk_bf16_f32(a, b));
}
#else
__device__ __forceinline__ unsigned pk2(float a, float b) {
  union { float f; unsigned u; } x, y; x.f = a; y.f = b;
  return __builtin_amdgcn_perm(y.u + 0x8000u, x.u + 0x8000u, 0x07060302u);
}
#endif

__device__ __forceinline__ short8 u2s8(uint4 u) {
  union { uint4 a; short8 b; } c; c.a = u; return c.b;
}

// compiler-level ordering within a wave (validated R5/R6)
__device__ __forceinline__ void wave_mem_fence() {
  asm volatile("" ::: "memory");
  __builtin_amdgcn_wave_barrier();
  asm volatile("" ::: "memory");
}

// async copy: 64 lanes x 16B = 1 KB chunk, global -> LDS (width-16 variant)
__device__ __forceinline__ void gload16(const unsigned short* g, unsigned short* l) {
  __builtin_amdgcn_global_load_lds((glb_us*)g, (lds_us*)l, 16, 0, 0);
}

// acos(z)/pi, z clipped to [-1,1].
__device__ __forceinline__ float acos01(float z) {
  float ax = fminf(fabsf(z), 1.0f);
  float t  = __builtin_amdgcn_sqrtf(1.0f - ax);
  float p  = fmaf(ax, fmaf(ax, fmaf(ax, -0.00596110f, 0.02363618f),
                           -0.06751692f), 0.49998766f);
  p *= t;
  return z >= 0.0f ? p : 1.0f - p;
}

// atan2(y,x)/(2pi) + 0.5  in [0,1].
__device__ __forceinline__ float atan2_01(float y, float x) {
  float ax = fabsf(x), ay = fabsf(y);
  float hi = fmaxf(ax, ay), lo = fminf(ax, ay);
  float r  = lo * __builtin_amdgcn_rcpf(fmaxf(hi, 1e-30f));
  float r2 = r * r;
  float p  = fmaf(r2, fmaf(r2, fmaf(r2, fmaf(r2, fmaf(r2,
               -0.0018655370f, 0.0083800422f), -0.018531250f),
                0.030803547f), -0.052940457f), 0.159151323f);
  float q  = r * p;
  q = (ay > ax) ? 0.25f - q : q;
  q = (x < 0.0f) ? 0.5f - q : q;
  return 0.5f + ((y >= 0.0f) ? q : -q);
}

// gaussian one-blob, 4 bins -> two packed dwords
__device__ __forceinline__ uint2 blob4pk(float x) {
  float x4 = x * 4.0f;
  float e0, e1, e2, e3;
  { float t = x4 - 0.5f; e0 = __builtin_amdgcn_exp2f(t * t * -0.72134752f); }
  { float t = x4 - 1.5f; e1 = __builtin_amdgcn_exp2f(t * t * -0.72134752f); }
  { float t = x4 - 2.5f; e2 = __builtin_amdgcn_exp2f(t * t * -0.72134752f); }
  { float t = x4 - 3.5f; e3 = __builtin_amdgcn_exp2f(t * t * -0.72134752f); }
  return make_uint2(pk2(e0, e1), pk2(e2, e3));
}

// bf16 weights in d_ws, stored in WAVE-CONSUMPTION order so global_load_lds
// (wave-uniform base + lane*16B, no scatter) copies verbatim and ds_read_b128
// at lane*16 is conflict-free:
//   hidden: wb[l*4096 + ((t*2+h)*64 + lane)*8 + j]
//           = W_l[sigma-row(t,n15)][h*32 + q*8 + j],  lane=q*16+n15
//   sigma-row(t,n15) = 32*(t>>1) + 8*(n15>>2) + 4*(t&1) + (n15&3)
//   W6:     wb[24576 + (h*64 + lane)*8 + j] = W6[n15][h*32+q*8+j] (n15<3, else 0)
__global__ void prep_weights(
    const float* __restrict__ W0, const float* __restrict__ W1,
    const float* __restrict__ W2, const float* __restrict__ W3,
    const float* __restrict__ W4, const float* __restrict__ W5,
    const float* __restrict__ W6, unsigned short* __restrict__ wb)
{
  int idx = blockIdx.x * blockDim.x + threadIdx.x;
  if (idx < 24576) {
    int l = idx >> 12;
    const float* W = (l==0)?W0:(l==1)?W1:(l==2)?W2:(l==3)?W3:(l==4)?W4:W5;
    int j   = idx & 7;
    int ln  = (idx >> 3) & 63;
    int h   = (idx >> 9) & 1;
    int t   = (idx >> 10) & 3;
    int n15 = ln & 15, q = ln >> 4;
    int src = 32*(t>>1) + 8*(n15>>2) + 4*(t&1) + (n15&3);
    int col = h*32 + q*8 + j;
    wb[idx] = f2bf(W[src*64 + col]);
  } else if (idx < 25600) {
    int i6  = idx - 24576;
    int j   = i6 & 7;
    int ln  = (i6 >> 3) & 63;
    int h   = (i6 >> 9) & 1;
    int n15 = ln & 15, q = ln >> 4;
    wb[idx] = (n15 < 3) ? f2bf(W6[n15*64 + h*32 + q*8 + j]) : (unsigned short)0;
  }
}

// 64 rows/wave, 4 waves/block. X per-wave private (wave fences). Weights
// stream through a 16 KB LDS double-buffer via global_load_lds, prefetched
// one full layer ahead; end-of-layer __syncthreads drains vmcnt (m97
// semantics) so weight latency is fully hidden. 53248 B LDS -> 3 blocks/CU.
__global__ __launch_bounds__(256, 3) void nrc_mlp(
    const float* __restrict__ P, const float* __restrict__ WI,
    const float* __restrict__ NRM, const float* __restrict__ ALPHA,
    const float* __restrict__ BETA, const float* __restrict__ R,
    const unsigned short* __restrict__ wb, float* __restrict__ out)
{
  __shared__ __align__(16) unsigned short Wlds[8192];       // 16384 B dbuf
  __shared__ __align__(16) unsigned short xlds[4][64][72];  // 36864 B
  const int lane = threadIdx.x & 63;
  const int wv   = threadIdx.x >> 6;
  unsigned short (* __restrict__ X)[72] = xlds[wv];
  const int n15 = lane & 15;
  const int q   = lane >> 4;
  const int row0 = (blockIdx.x * 4 + wv) * 64;
  const int l16 = lane * 8;          // shorts: lane*16 bytes

  // -------- issue W0 prefetch into buf0 (hidden under encode) --------
  {
    int c0 = 2*wv*512;               // this wave's two 1KB chunks
    gload16(wb + c0 + l16,        Wlds + c0 + l16);
    gload16(wb + c0 + 512 + l16,  Wlds + c0 + 512 + l16);
  }

  // ---------------- encoding: lane <-> row ----------------
  {
    const int row = row0 + lane;
    unsigned short* xr = &X[lane][0];

    float s0[6], c0[6], s1[6], c1[6], s2[6], c2[6];
    {
      float rev = 0.5f * P[row*3+0];
#pragma unroll
      for (int i = 0; i < 6; ++i) {
        float fr = __builtin_amdgcn_fractf(rev);
        s0[i] = __builtin_amdgcn_sinf(fr);
        c0[i] = __builtin_amdgcn_cosf(fr);
        rev = rev + rev;
      }
      rev = 0.5f * P[row*3+1];
#pragma unroll
      for (int i = 0; i < 6; ++i) {
        float fr = __builtin_amdgcn_fractf(rev);
        s1[i] = __builtin_amdgcn_sinf(fr);
        c1[i] = __builtin_amdgcn_cosf(fr);
        rev = rev + rev;
      }
      rev = 0.5f * P[row*3+2];
#pragma unroll
      for (int i = 0; i < 6; ++i) {
        float fr = __builtin_amdgcn_fractf(rev);
        s2[i] = __builtin_amdgcn_sinf(fr);
        c2[i] = __builtin_amdgcn_cosf(fr);
        rev = rev + rev;
      }
    }
    *(uint4*)(xr +  0) = make_uint4(pk2(s0[0],s0[1]), pk2(s0[2],s0[3]),
                                    pk2(s0[4],s0[5]), pk2(c0[0],c0[1]));
    *(uint4*)(xr +  8) = make_uint4(pk2(c0[2],c0[3]), pk2(c0[4],c0[5]),
                                    pk2(s1[0],s1[1]), pk2(s1[2],s1[3]));
    *(uint4*)(xr + 16) = make_uint4(pk2(s1[4],s1[5]), pk2(c1[0],c1[1]),
                                    pk2(c1[2],c1[3]), pk2(c1[4],c1[5]));
    *(uint4*)(xr + 24) = make_uint4(pk2(s2[0],s2[1]), pk2(s2[2],s2[3]),
                                    pk2(s2[4],s2[5]), pk2(c2[0],c2[1]));

    uint2 bwt, bwp, bnt, bnp, brr;
    {
      float wx = WI[row*3+0], wy = WI[row*3+1], wz = WI[row*3+2];
      bwt = blob4pk(acos01(wz));
      bwp = blob4pk(atan2_01(wy, wx));
    }
    {
      float nx = NRM[row*3+0], ny = NRM[row*3+1], nz = NRM[row*3+2];
      bnt = blob4pk(acos01(nz));
      bnp = blob4pk(atan2_01(ny, nx));
    }
    brr = blob4pk(1.0f - __builtin_amdgcn_exp2f(R[row] * -1.44269504f));

    *(uint4*)(xr + 32) = make_uint4(pk2(c2[2],c2[3]), pk2(c2[4],c2[5]),
                                    bwt.x, bwt.y);
    *(uint4*)(xr + 40) = make_uint4(bwp.x, bwp.y, bnt.x, bnt.y);
    *(uint4*)(xr + 48) = make_uint4(bnp.x, bnp.y, brr.x, brr.y);

    float a0 = ALPHA[row*3+0], a1 = ALPHA[row*3+1], a2 = ALPHA[row*3+2];
    float e0 = BETA[row*3+0],  e1 = BETA[row*3+1],  e2 = BETA[row*3+2];
    *(uint4*)(xr + 56) = make_uint4(pk2(a0,a1), pk2(a2,e0), pk2(e1,e2),
                                    0x3F803F80u);
  }
  wave_mem_fence();   // X writes -> X reads (same wave; DS in-order)

  // ---------------- initial B-fragments (4 groups of 16 rows) ----------
  uint4 b0[4], b1[4];
#pragma unroll
  for (int g = 0; g < 4; ++g) {
    b0[g] = *(const uint4*)(&X[g*16 + n15][q*8]);
    b1[g] = *(const uint4*)(&X[g*16 + n15][32 + q*8]);
  }

  __syncthreads();    // drains W0 prefetch (vmcnt) for all waves

  const f32x4 z = {0.f, 0.f, 0.f, 0.f};

  // ---------------- 6 hidden layers; weights via LDS dbuf ----------------
#pragma unroll
  for (int l = 0; l < 6; ++l) {
    // prefetch next layer's weights (or W6) into the other buffer
    if (l < 5) {
      int nb = ((l+1) & 1) * 4096;
      int ns = (l+1) * 4096;
      int c0 = 2*wv*512;
      gload16(wb + ns + c0 + l16,       Wlds + nb + c0 + l16);
      gload16(wb + ns + c0 + 512 + l16, Wlds + nb + c0 + 512 + l16);
    } else {
      if (wv < 2) {
        int c0 = wv*512;
        gload16(wb + 24576 + c0 + l16, Wlds + c0 + l16);  // W6 -> buf0
      }
    }

    const unsigned short* Wb = Wlds + (l & 1) * 4096;
    short8 a0[4], a1[4];
#pragma unroll
    for (int t = 0; t < 4; ++t) {
      a0[t] = *(const short8*)(Wb + t*1024 + l16);
      a1[t] = *(const short8*)(Wb + t*1024 + 512 + l16);
    }
#pragma unroll
    for (int g = 0; g < 4; ++g) {
      short8 bb0 = u2s8(b0[g]);
      short8 bb1 = u2s8(b1[g]);
      f32x4 acc[4];
#pragma unroll
      for (int t = 0; t < 4; ++t) {
        f32x4 c = __builtin_amdgcn_mfma_f32_16x16x32_bf16(a0[t], bb0, z, 0, 0, 0);
        acc[t]  = __builtin_amdgcn_mfma_f32_16x16x32_bf16(a1[t], bb1, c, 0, 0, 0);
      }
      uint4 n0, n1;
      n0.x = pk2(fmaxf(acc[0][0],0.f), fmaxf(acc[0][1],0.f));
      n0.y = pk2(fmaxf(acc[0][2],0.f), fmaxf(acc[0][3],0.f));
      n0.z = pk2(fmaxf(acc[1][0],0.f), fmaxf(acc[1][1],0.f));
      n0.w = pk2(fmaxf(acc[1][2],0.f), fmaxf(acc[1][3],0.f));
      n1.x = pk2(fmaxf(acc[2][0],0.f), fmaxf(acc[2][1],0.f));
      n1.y = pk2(fmaxf(acc[2][2],0.f), fmaxf(acc[2][3],0.f));
      n1.z = pk2(fmaxf(acc[3][0],0.f), fmaxf(acc[3][1],0.f));
      n1.w = pk2(fmaxf(acc[3][2],0.f), fmaxf(acc[3][3],0.f));
      b0[g] = n0; b1[g] = n1;
    }
    __syncthreads();  // publishes next-layer weights (vmcnt drained) +
                      // protects the buffer being re-prefetched next layer
  }

  // -------- output layer (W6 in buf0) + fused scale + direct store --------
  {
    short8 o0 = *(const short8*)(Wlds + l16);
    short8 o1 = *(const short8*)(Wlds + 512 + l16);
#pragma unroll
    for (int g = 0; g < 4; ++g) {
      f32x4 c = __builtin_amdgcn_mfma_f32_16x16x32_bf16(o0, u2s8(b0[g]), z, 0, 0, 0);
      c       = __builtin_amdgcn_mfma_f32_16x16x32_bf16(o1, u2s8(b1[g]), c, 0, 0, 0);
      if (q == 0) {
        int base = row0*3 + g*48 + n15*3;
        float3 av = *(const float3*)(ALPHA + base);
        float3 bv = *(const float3*)(BETA + base);
        float3 o;
        o.x = c[0] * (av.x + bv.x);
        o.y = c[1] * (av.y + bv.y);
        o.z = c[2] * (av.z + bv.z);
        *(float3*)(out + base) = o;
      }
    }
  }
}

extern "C" void kernel_launch(void* const* d_in, const int* in_sizes, int n_in,
                              void* d_out, int out_size, void* d_ws, size_t ws_size,
                              hipStream_t stream) {
  const float* P  = (const float*)d_in[0];
  const float* WI = (const float*)d_in[1];
  const float* NR = (const float*)d_in[2];
  const float* AL = (const float*)d_in[3];
  const float* BE = (const float*)d_in[4];
  const float* R  = (const float*)d_in[5];
  const float* W0 = (const float*)d_in[6];
  const float* W1 = (const float*)d_in[7];
  const float* W2 = (const float*)d_in[8];
  const float* W3 = (const float*)d_in[9];
  const float* W4 = (const float*)d_in[10];
  const float* W5 = (const float*)d_in[11];
  const float* W6 = (const float*)d_in[12];
  unsigned short* wb = (unsigned short*)d_ws;   // 25600 bf16 = 51200 B
  float* out = (float*)d_out;

  prep_weights<<<100, 256, 0, stream>>>(W0, W1, W2, W3, W4, W5, W6, wb);
  nrc_mlp<<<4096, 256, 0, stream>>>(P, WI, NR, AL, BE, R, wb, out);
}